// Round 3
// baseline (297.656 us; speedup 1.0000x reference)
//
#include <hip/hip_runtime.h>

// TTLinear fused v2: out = x @ (core0 @ core1)^T + bias, rank-8.
// Phase A redesign vs v1: core1 is staged into LDS (double-buffered) so the
// global-load stream is PURE x (independent float4s per lane) -> latency
// hiding via many outstanding x loads instead of L2-latency core1 re-reads.
// Block = 8 tokens x 32 lanes/token; chunk = 512 floats of i; 8 chunks.
// Phase B unchanged: expand 8 tokens x 4096 outputs, coalesced float4 stores.

#define TOKENS 8192
#define IN_F   4096
#define OUT_F  4096
#define RANK   8
#define TPB_T  8          // tokens per block
#define CHUNK  512        // i-chunk in floats
#define NCHUNK (IN_F / CHUNK)   // 8

__global__ __launch_bounds__(256, 4) void tt_fused2(const float* __restrict__ x,
                                                    const float* __restrict__ core0,
                                                    const float* __restrict__ core1,
                                                    const float* __restrict__ bias,
                                                    float* __restrict__ out) {
    __shared__ float c1s[2][RANK][CHUNK];   // 2 x 16 KB double-buffered core1 chunk
    __shared__ float y_s[TPB_T][RANK];      // 256 B

    const int tid   = threadIdx.x;
    const int t0    = blockIdx.x * TPB_T;
    const int t_loc = tid >> 5;             // 0..7 (wave = 2 tokens x 32 lanes)
    const int j     = tid & 31;             // lane's column-slot within token

    const float* xrow = x + (size_t)(t0 + t_loc) * IN_F;

    // ---- prologue: stage core1 chunk 0 into buf 0; preload x chunk 0 ----
    #pragma unroll
    for (int m = 0; m < 4; ++m) {
        const int idx = tid + 256 * m;          // 1024 float4 per chunk
        const int r = idx >> 7, c4 = idx & 127; // 128 float4 per rank-row
        *(float4*)&c1s[0][r][c4 * 4] = *(const float4*)(core1 + r * IN_F + c4 * 4);
    }
    float4 xv[4];
    #pragma unroll
    for (int g = 0; g < 4; ++g)
        xv[g] = *(const float4*)(xrow + j * 4 + g * 128);
    __syncthreads();

    float acc[RANK];
    #pragma unroll
    for (int r = 0; r < RANK; ++r) acc[r] = 0.f;

    // ---- main loop over i-chunks, double-buffered c1, prefetched x ----
    for (int c = 0; c < NCHUNK; ++c) {
        const int buf = c & 1;

        // prefetch next chunk's x (independent float4 loads)
        float4 xn[4];
        if (c + 1 < NCHUNK) {
            #pragma unroll
            for (int g = 0; g < 4; ++g)
                xn[g] = *(const float4*)(xrow + (c + 1) * CHUNK + j * 4 + g * 128);
        }
        // prefetch next chunk's core1 (global -> regs; L2-resident)
        float4 st[4];
        if (c + 1 < NCHUNK) {
            #pragma unroll
            for (int m = 0; m < 4; ++m) {
                const int idx = tid + 256 * m;
                const int r = idx >> 7, c4 = idx & 127;
                st[m] = *(const float4*)(core1 + r * IN_F + (c + 1) * CHUNK + c4 * 4);
            }
        }

        // compute on current buffer: lanes 32..63 read same LDS addrs as 0..31
        // (same-address broadcast, conflict-free); j spans 512 B contiguous.
        #pragma unroll
        for (int g = 0; g < 4; ++g) {
            #pragma unroll
            for (int r = 0; r < RANK; ++r) {
                const float4 cv = *(const float4*)&c1s[buf][r][j * 4 + g * 128];
                acc[r] += xv[g].x * cv.x + xv[g].y * cv.y
                        + xv[g].z * cv.z + xv[g].w * cv.w;
            }
        }

        // commit staged core1 into the other buffer; roll x regs
        if (c + 1 < NCHUNK) {
            #pragma unroll
            for (int m = 0; m < 4; ++m) {
                const int idx = tid + 256 * m;
                const int r = idx >> 7, c4 = idx & 127;
                *(float4*)&c1s[buf ^ 1][r][c4 * 4] = st[m];
            }
            #pragma unroll
            for (int g = 0; g < 4; ++g) xv[g] = xn[g];
        }
        __syncthreads();
    }

    // ---- reduce partials across the 32 j-lanes of each token group ----
    #pragma unroll
    for (int r = 0; r < RANK; ++r) {
        #pragma unroll
        for (int off = 1; off <= 16; off <<= 1)
            acc[r] += __shfl_xor(acc[r], off, 64);
    }
    if (j == 0) {
        #pragma unroll
        for (int r = 0; r < RANK; ++r) y_s[t_loc][r] = acc[r];
    }
    __syncthreads();

    // ---- Phase B: out[t][o] = bias[o] + sum_r y[t][r]*core0[o][r] ----
    for (int jj = 0; jj < 4; ++jj) {
        const int o = jj * 1024 + tid * 4;

        float4 w[8];
        #pragma unroll
        for (int q = 0; q < 4; ++q) {
            w[2 * q]     = *(const float4*)(core0 + (o + q) * RANK);
            w[2 * q + 1] = *(const float4*)(core0 + (o + q) * RANK + 4);
        }
        const float4 b = *(const float4*)(bias + o);

        #pragma unroll
        for (int t = 0; t < TPB_T; ++t) {
            const float4 y0 = *(const float4*)(&y_s[t][0]);
            const float4 y1 = *(const float4*)(&y_s[t][4]);
            float4 cc;
            cc.x = b.x + y0.x * w[0].x + y0.y * w[0].y + y0.z * w[0].z + y0.w * w[0].w
                       + y1.x * w[1].x + y1.y * w[1].y + y1.z * w[1].z + y1.w * w[1].w;
            cc.y = b.y + y0.x * w[2].x + y0.y * w[2].y + y0.z * w[2].z + y0.w * w[2].w
                       + y1.x * w[3].x + y1.y * w[3].y + y1.z * w[3].z + y1.w * w[3].w;
            cc.z = b.z + y0.x * w[4].x + y0.y * w[4].y + y0.z * w[4].z + y0.w * w[4].w
                       + y1.x * w[5].x + y1.y * w[5].y + y1.z * w[5].z + y1.w * w[5].w;
            cc.w = b.w + y0.x * w[6].x + y0.y * w[6].y + y0.z * w[6].z + y0.w * w[6].w
                       + y1.x * w[7].x + y1.y * w[7].y + y1.z * w[7].z + y1.w * w[7].w;
            *(float4*)(out + (size_t)(t0 + t) * OUT_F + o) = cc;
        }
    }
}

extern "C" void kernel_launch(void* const* d_in, const int* in_sizes, int n_in,
                              void* d_out, int out_size, void* d_ws, size_t ws_size,
                              hipStream_t stream) {
    const float* x     = (const float*)d_in[0];  // [8192, 4096]
    const float* core0 = (const float*)d_in[1];  // [1, 4096, 8] -> [o][r]
    const float* core1 = (const float*)d_in[2];  // [8, 4096, 1] -> [r][i]
    const float* bias  = (const float*)d_in[3];  // [4096]
    float* out = (float*)d_out;                  // [8192, 4096]

    tt_fused2<<<TOKENS / TPB_T, 256, 0, stream>>>(x, core0, core1, bias, out);
}